// Round 1
// baseline (2721.783 us; speedup 1.0000x reference)
//
#include <hip/hip_runtime.h>
#include <stdint.h>

typedef unsigned short u16;
typedef __attribute__((ext_vector_type(8))) short bf16x8;
typedef __attribute__((ext_vector_type(4))) float fx4;

#define MFMA16(a, b, c) __builtin_amdgcn_mfma_f32_16x16x32_bf16((a), (b), (c), 0, 0, 0)

// ---- workspace layout (bytes) ----
// CSAVE: per-group 16 KiB blocks overlaying each group's OWN X region:
// group g's block = X[b=16g][t=0..31] (bytes g*4194304 .. +16384). That
// region is read only by group g at steps t<=31 and written only after the
// group's final step; the intra-group sum-barrier provably bounds member
// drift to 1 step, so all members are at step >=511 when any writes csave.
// (The old layout put csave rows 16..255 inside X[b=0] — a cross-group race:
// a leading group corrupted x-data group 0 had not yet read -> NaN.)
#define OFF_X      0u            // x bf16 [B][L][256]             67108864
#define OFF_H      67108864u     // H bf16 [577][256][256] rotating 75628544
#define OFF_ENCWT  142737408u    // enc_W^T bf16 [1024][256]         524288
#define OFF_ENCUT  143261696u    // enc_U^T bf16 [1024][256]         524288
#define OFF_CELLT  143785984u    // (cell_W+cell_U)^T bf16           524288
#define OFF_CONVKT 144310272u    // conv k^T bf16 [256][320]         163840
#define OFF_BWT    144474112u    // back_W^T bf16 [64][256]           32768
#define OFF_FWT    144506880u    // fore_W^T bf16 [32][256]           16384
#define OFF_BAR    144523264u    // 16 barrier counters, 64B apart     1024
// end: 144524288 bytes

__device__ __forceinline__ u16 f2bf(float f) {
    uint32_t u = __builtin_bit_cast(uint32_t, f);
    u += 0x7FFFu + ((u >> 16) & 1u);   // RNE
    return (u16)(u >> 16);
}
__device__ __forceinline__ float sigm(float x) { return 1.0f / (1.0f + __expf(-x)); }
__device__ __forceinline__ float tanh_f(float x) { return 1.0f - 2.0f / (__expf(2.0f * x) + 1.0f); }

// store 2 bytes bypassing L1/L2 -> lands at device-coherent point (L3)
__device__ __forceinline__ void store_h_sc(const u16* p, uint32_t v) {
    asm volatile("global_store_short %0, %1, off sc0 sc1" :: "v"(p), "v"(v) : "memory");
}
// drain all vector-memory ops (incl. the asm sc stores the compiler can't see)
__device__ __forceinline__ void vmcnt0() { asm volatile("s_waitcnt vmcnt(0)" ::: "memory"); }

// ---------------------------------------------------------------------------
__global__ void zero_kernel(unsigned char* ws) {
    int i = blockIdx.x * blockDim.x + threadIdx.x;   // 16384 threads
    uint32_t* h0 = (uint32_t*)(ws + OFF_H);          // slot 0: 131072 B
    for (int k = i; k < 32768; k += 16384) h0[k] = 0u;
    if (i < 256) ((uint32_t*)(ws + OFF_BAR))[i] = 0u;
}

// ---------------------------------------------------------------------------
__global__ void prep_kernel(const float* enc_W, const float* enc_U, const float* cell_W,
                            const float* cell_U, const float* conv_k, const float* back_W,
                            const float* fore_W, unsigned char* ws) {
    u16* encWt = (u16*)(ws + OFF_ENCWT);
    u16* encUt = (u16*)(ws + OFF_ENCUT);
    u16* cellT = (u16*)(ws + OFF_CELLT);
    u16* convKt = (u16*)(ws + OFF_CONVKT);
    u16* bwt = (u16*)(ws + OFF_BWT);
    u16* fwt = (u16*)(ws + OFF_FWT);
    int idx = blockIdx.x * blockDim.x + threadIdx.x;
    int stride = gridDim.x * blockDim.x;
    for (int i = idx; i < 262144; i += stride) {
        int n = i >> 8, k = i & 255;
        encWt[i] = f2bf(enc_W[k * 1024 + n]);
        encUt[i] = f2bf(enc_U[k * 1024 + n]);
        cellT[i] = f2bf(cell_W[k * 1024 + n] + cell_U[k * 1024 + n]);
    }
    for (int i = idx; i < 81920; i += stride) {
        int u = i / 320, rem = i - u * 320;
        convKt[i] = f2bf(conv_k[rem * 256 + u]);
    }
    for (int i = idx; i < 16384; i += stride) {
        int n = i >> 8, k = i & 255;
        bwt[i] = f2bf(back_W[k * 64 + n]);
    }
    for (int i = idx; i < 8192; i += stride) {
        int n = i >> 8, k = i & 255;
        fwt[i] = f2bf(fore_W[k * 32 + n]);
    }
}

// ---------------------------------------------------------------------------
// Conv1D(same,k=5)+bias+ReLU as MFMA GEMM (unchanged from round 1)
__global__ __launch_bounds__(256) void conv_kernel(const float* __restrict__ in,
                                                   const float* __restrict__ conv_b,
                                                   unsigned char* ws) {
    const u16* kt = (const u16*)(ws + OFF_CONVKT);
    u16* xout = (u16*)(ws + OFF_X);
    int w = threadIdx.x >> 6, lane = threadIdx.x & 63;
    int m = lane & 15, q = lane >> 4;
    int mt = blockIdx.x * 4 + w;
    int r0 = mt * 16;
    int b = r0 >> 9;
    int l0 = r0 & 511;

    fx4 acc[16];
#pragma unroll
    for (int nt = 0; nt < 16; ++nt) acc[nt] = (fx4){0.f, 0.f, 0.f, 0.f};

#pragma unroll
    for (int s = 0; s < 10; ++s) {
        int k0 = s * 32 + q * 8;
        int kk = k0 >> 6, c = k0 & 63;
        int l2 = l0 + m + kk - 2;
        bf16x8 af = {0, 0, 0, 0, 0, 0, 0, 0};
        if (l2 >= 0 && l2 < 512) {
            const float* src = in + (((b << 9) + l2) << 6) + c;
            fx4 f0 = *(const fx4*)src;
            fx4 f1 = *(const fx4*)(src + 4);
            af[0] = (short)f2bf(f0[0]); af[1] = (short)f2bf(f0[1]);
            af[2] = (short)f2bf(f0[2]); af[3] = (short)f2bf(f0[3]);
            af[4] = (short)f2bf(f1[0]); af[5] = (short)f2bf(f1[1]);
            af[6] = (short)f2bf(f1[2]); af[7] = (short)f2bf(f1[3]);
        }
#pragma unroll
        for (int nt = 0; nt < 16; ++nt) {
            bf16x8 bf = *(const bf16x8*)(kt + (nt * 16 + m) * 320 + k0);
            acc[nt] = MFMA16(af, bf, acc[nt]);
        }
    }
#pragma unroll
    for (int nt = 0; nt < 16; ++nt) {
        int u = nt * 16 + m;
        float bias = conv_b[u];
#pragma unroll
        for (int r = 0; r < 4; ++r) {
            float v = acc[nt][r] + bias;
            v = v > 0.f ? v : 0.f;
            int row = r0 + q * 4 + r;
            xout[row * 256 + u] = f2bf(v);
        }
    }
}

// ---------------------------------------------------------------------------
// Encoder: 512 steps. 64 WGs = 16 groups (g=bid&15, 16 batch rows) x 4 members
// (p=bid>>4, 64 hidden units each). Wave w owns 16 units; W/U fragments in
// VGPRs. h exchange: sc0sc1 stores into rotating H[t] + relaxed agent atomics.
// No fences anywhere: exchange data lives at the device-coherent point, and
// peer reads hit never-before-cached lines (rotating buffer).
// Intra-group sum-barrier (bar >= 4t) bounds member drift to <=1 step:
// a member passing poll t implies ALL members have completed step t-1.
__global__ __launch_bounds__(256, 1) void enc_kernel(const float* __restrict__ enc_b,
                                                     unsigned char* ws) {
    int tid = threadIdx.x;
    int w = tid >> 6, lane = tid & 63, m = lane & 15, q = lane >> 4;
    int bid = blockIdx.x;
    int g = bid & 15, p = bid >> 4;
    int b0 = g * 16;
    int un0 = p * 64 + w * 16;

    const u16* encWt = (const u16*)(ws + OFF_ENCWT);
    const u16* encUt = (const u16*)(ws + OFF_ENCUT);
    const u16* xbf = (const u16*)(ws + OFF_X);
    u16* H = (u16*)(ws + OFF_H);
    // per-group csave block overlays this group's OWN X[b=16g][t<32] (dead by
    // the time any member writes it; see layout comment at top)
    float* csaveg = (float*)(ws + OFF_X + (size_t)g * 4194304u);
    int* bar = (int*)(ws + OFF_BAR + g * 64);

    bf16x8 wfrag[4][8], ufrag[4][8];
#pragma unroll
    for (int gi = 0; gi < 4; ++gi) {
#pragma unroll
        for (int s = 0; s < 8; ++s) {
            int n = gi * 256 + un0 + m;
            wfrag[gi][s] = *(const bf16x8*)(encWt + n * 256 + s * 32 + q * 8);
            ufrag[gi][s] = *(const bf16x8*)(encUt + n * 256 + s * 32 + q * 8);
        }
    }
    float bi[4], creg[4];
#pragma unroll
    for (int gi = 0; gi < 4; ++gi) bi[gi] = enc_b[gi * 256 + un0 + m];
    creg[0] = creg[1] = creg[2] = creg[3] = 0.f;

    const u16* xrow = xbf + (size_t)(b0 + m) * (512 * 256) + q * 8;

    for (int t = 0; t < 512; ++t) {
        // ---- x part: independent of peers; overlaps their h-chain ----
        bf16x8 xa[8];
        const u16* xA = xrow + (size_t)t * 256;
#pragma unroll
        for (int s = 0; s < 8; ++s) xa[s] = *(const bf16x8*)(xA + s * 32);
        fx4 acc[4];
#pragma unroll
        for (int gi = 0; gi < 4; ++gi) acc[gi] = (fx4){bi[gi], bi[gi], bi[gi], bi[gi]};
#pragma unroll
        for (int s = 0; s < 8; ++s) {
#pragma unroll
            for (int gi = 0; gi < 4; ++gi)
                acc[gi] = MFMA16(xa[s], wfrag[gi][s], acc[gi]);
        }

        // ---- wait for all 16 group-waves to have finished step t-1 ----
        if (lane == 0) {
            int tgt = 4 * t;
            while (__hip_atomic_load(bar, __ATOMIC_RELAXED, __HIP_MEMORY_SCOPE_AGENT) < tgt) {}
        }
        asm volatile("" ::: "memory");   // don't hoist ha loads above the poll

        // ---- h part ----
        const u16* hA = H + (size_t)t * 65536 + (b0 + m) * 256 + q * 8;
        bf16x8 ha[8];
#pragma unroll
        for (int s = 0; s < 8; ++s) ha[s] = *(const bf16x8*)(hA + s * 32);
#pragma unroll
        for (int s = 0; s < 8; ++s) {
#pragma unroll
            for (int gi = 0; gi < 4; ++gi)
                acc[gi] = MFMA16(ha[s], ufrag[gi][s], acc[gi]);
        }

        // ---- gates + h store to slot t+1 (sc0 sc1: straight to L3) ----
        const u16* hw = H + (size_t)(t + 1) * 65536 + un0 + m;
#pragma unroll
        for (int r = 0; r < 4; ++r) {
            float cv = sigm(acc[1][r]) * creg[r] + sigm(acc[0][r]) * tanh_f(acc[2][r]);
            creg[r] = cv;
            float hv = sigm(acc[3][r]) * tanh_f(cv);
            store_h_sc(hw + (b0 + q * 4 + r) * 256, (uint32_t)f2bf(hv));
        }
        vmcnt0();          // stores device-visible before the signal
        __syncthreads();   // all 4 waves of this WG drained
        if (tid == 0)
            __hip_atomic_fetch_add(bar, 1, __ATOMIC_RELAXED, __HIP_MEMORY_SCOPE_AGENT);
    }

    // hand off c to the decoder (normal stores; kernel-end flush makes visible)
    // local row = q*4+r (0..15), cols un0..un0+15 of this group's private block
#pragma unroll
    for (int r = 0; r < 4; ++r)
        csaveg[(q * 4 + r) * 256 + un0 + m] = creg[r];
}

// ---------------------------------------------------------------------------
// Decoder: 64 steps, input = previous h, combined (cell_W+cell_U).
__global__ __launch_bounds__(256, 1) void dec_kernel(const float* __restrict__ cell_b,
                                                     unsigned char* ws) {
    int tid = threadIdx.x;
    int w = tid >> 6, lane = tid & 63, m = lane & 15, q = lane >> 4;
    int bid = blockIdx.x;
    int g = bid & 15, p = bid >> 4;
    int b0 = g * 16;
    int un0 = p * 64 + w * 16;

    const u16* cellT = (const u16*)(ws + OFF_CELLT);
    u16* H = (u16*)(ws + OFF_H);
    const float* csaveg = (const float*)(ws + OFF_X + (size_t)g * 4194304u);
    int* bar = (int*)(ws + OFF_BAR + g * 64);

    bf16x8 wfrag[4][8];
#pragma unroll
    for (int gi = 0; gi < 4; ++gi) {
#pragma unroll
        for (int s = 0; s < 8; ++s)
            wfrag[gi][s] = *(const bf16x8*)(cellT + (gi * 256 + un0 + m) * 256 + s * 32 + q * 8);
    }
    float bi[4], creg[4];
#pragma unroll
    for (int gi = 0; gi < 4; ++gi) bi[gi] = cell_b[gi * 256 + un0 + m];
#pragma unroll
    for (int r = 0; r < 4; ++r) creg[r] = csaveg[(q * 4 + r) * 256 + un0 + m];

    for (int t = 0; t < 64; ++t) {
        if (lane == 0) {
            int tgt = 2048 + 4 * t;   // encoder left counter at 4*512 = 2048
            while (__hip_atomic_load(bar, __ATOMIC_RELAXED, __HIP_MEMORY_SCOPE_AGENT) < tgt) {}
        }
        asm volatile("" ::: "memory");

        const u16* hA = H + (size_t)(512 + t) * 65536 + (b0 + m) * 256 + q * 8;
        bf16x8 ha[8];
#pragma unroll
        for (int s = 0; s < 8; ++s) ha[s] = *(const bf16x8*)(hA + s * 32);
        fx4 acc[4];
#pragma unroll
        for (int gi = 0; gi < 4; ++gi) acc[gi] = (fx4){bi[gi], bi[gi], bi[gi], bi[gi]};
#pragma unroll
        for (int s = 0; s < 8; ++s) {
#pragma unroll
            for (int gi = 0; gi < 4; ++gi)
                acc[gi] = MFMA16(ha[s], wfrag[gi][s], acc[gi]);
        }

        const u16* hw = H + (size_t)(513 + t) * 65536 + un0 + m;
#pragma unroll
        for (int r = 0; r < 4; ++r) {
            float cv = sigm(acc[1][r]) * creg[r] + sigm(acc[0][r]) * tanh_f(acc[2][r]);
            creg[r] = cv;
            float hv = sigm(acc[3][r]) * tanh_f(cv);
            store_h_sc(hw + (b0 + q * 4 + r) * 256, (uint32_t)f2bf(hv));
        }
        vmcnt0();
        __syncthreads();
        if (tid == 0)
            __hip_atomic_fetch_add(bar, 1, __ATOMIC_RELAXED, __HIP_MEMORY_SCOPE_AGENT);
    }
}

// ---------------------------------------------------------------------------
// out[(b*seqlen+s)*ncols+col] = H-slot A[s][b][:] @ Bt[col][:] + bias[col]
__global__ __launch_bounds__(256) void out_gemm(const u16* __restrict__ A,
                                                const u16* __restrict__ Bt,
                                                const float* __restrict__ bias,
                                                float* __restrict__ out,
                                                int ncols, int seqlen) {
    int w = threadIdx.x >> 6, lane = threadIdx.x & 63, m = lane & 15, q = lane >> 4;
    int mt = blockIdx.x * 4 + w;
    int s = mt >> 4;
    int b0 = (mt & 15) * 16;
    bf16x8 af[8];
    const u16* Arow = A + ((size_t)s * 256 + b0 + m) * 256 + q * 8;
#pragma unroll
    for (int ss = 0; ss < 8; ++ss) af[ss] = *(const bf16x8*)(Arow + ss * 32);
    int ntiles = ncols >> 4;
    for (int nt = 0; nt < ntiles; ++nt) {
        fx4 acc = (fx4){0.f, 0.f, 0.f, 0.f};
#pragma unroll
        for (int ss = 0; ss < 8; ++ss) {
            bf16x8 bf = *(const bf16x8*)(Bt + (nt * 16 + m) * 256 + ss * 32 + q * 8);
            acc = MFMA16(af[ss], bf, acc);
        }
        int col = nt * 16 + m;
        float bv = bias[col];
#pragma unroll
        for (int r = 0; r < 4; ++r) {
            int b = b0 + q * 4 + r;
            out[((size_t)b * seqlen + s) * ncols + col] = acc[r] + bv;
        }
    }
}

// ---------------------------------------------------------------------------
extern "C" void kernel_launch(void* const* d_in, const int* in_sizes, int n_in,
                              void* d_out, int out_size, void* d_ws, size_t ws_size,
                              hipStream_t stream) {
    const float* inputs = (const float*)d_in[0];
    const float* conv_k = (const float*)d_in[1];
    const float* conv_b = (const float*)d_in[2];
    const float* enc_W  = (const float*)d_in[3];
    const float* enc_U  = (const float*)d_in[4];
    const float* enc_b  = (const float*)d_in[5];
    const float* cell_W = (const float*)d_in[6];
    const float* cell_U = (const float*)d_in[7];
    const float* cell_b = (const float*)d_in[8];
    const float* fore_W = (const float*)d_in[9];
    const float* fore_b = (const float*)d_in[10];
    const float* back_W = (const float*)d_in[11];
    const float* back_b = (const float*)d_in[12];
    unsigned char* ws = (unsigned char*)d_ws;
    float* out = (float*)d_out;

    zero_kernel<<<64, 256, 0, stream>>>(ws);
    prep_kernel<<<1024, 256, 0, stream>>>(enc_W, enc_U, cell_W, cell_U, conv_k, back_W, fore_W, ws);
    conv_kernel<<<2048, 256, 0, stream>>>(inputs, conv_b, ws);
    enc_kernel<<<64, 256, 0, stream>>>(enc_b, ws);
    dec_kernel<<<64, 256, 0, stream>>>(cell_b, ws);

    const u16* H = (const u16*)(ws + OFF_H);
    // backcast: slots 1..512 -> out[b][l][64] at float offset 524288
    out_gemm<<<2048, 256, 0, stream>>>(H + (size_t)1 * 65536, (const u16*)(ws + OFF_BWT),
                                       back_b, out + 524288, 64, 512);
    // forecast: slots 513..576 -> out[b][j][32]
    out_gemm<<<256, 256, 0, stream>>>(H + (size_t)513 * 65536, (const u16*)(ws + OFF_FWT),
                                      fore_b, out, 32, 64);
}

// Round 7
// 2334.826 us; speedup vs baseline: 1.1657x; 1.1657x over previous
//
#include <hip/hip_runtime.h>
#include <stdint.h>

typedef unsigned short u16;
typedef __attribute__((ext_vector_type(8))) short bf16x8;
typedef __attribute__((ext_vector_type(4))) float fx4;
typedef __attribute__((ext_vector_type(2))) unsigned int u32x2;

#define MFMA16(a, b, c) __builtin_amdgcn_mfma_f32_16x16x32_bf16((a), (b), (c), 0, 0, 0)

// ---- workspace layout (bytes) ----
// Identical to the round-1 PASSING layout. The z-ring (producers' x@W+b, fp32,
// 8 slots/group) lives in H[513..576], which is dead during enc_fused; the
// decoder (a separate, stream-ordered LATER kernel) overwrites it afterwards.
// CSAVE: per-group 16KB blocks overlaying each group's OWN X[b=16g][t<32]
// (proven safe in round 1: written only after the group's final enc step).
#define OFF_X      0u            // x bf16 [B][L][256]             67108864
#define OFF_H      67108864u     // H bf16 [577][256][256]         75628544
#define RING_OFF   134348800u    // = OFF_H + 513*131072; [16 g][8 slot][4 j][256 u][16 r] fp32
#define OFF_ENCWT  142737408u    // enc_W^T bf16 [1024][256]         524288
#define OFF_ENCUT  143261696u    // enc_U^T bf16 [1024][256]         524288
#define OFF_CELLT  143785984u    // (cell_W+cell_U)^T bf16           524288
#define OFF_CONVKT 144310272u    // conv k^T bf16 [256][320]         163840
#define OFF_BWT    144474112u    // back_W^T bf16 [64][256]           32768
#define OFF_FWT    144506880u    // fore_W^T bf16 [32][256]           16384
#define OFF_BAR    144523264u    // per group: hbar @g*64, pcnt_z @g*64+32
// end: 144524288 bytes (same as round 1)

// Watchdog: bounded spins -> a broken protocol becomes a diagnosable wrong
// answer instead of a container-killing hang.
#define POLL_BUDGET (1 << 25)

__device__ __forceinline__ u16 f2bf(float f) {
    uint32_t u = __builtin_bit_cast(uint32_t, f);
    u += 0x7FFFu + ((u >> 16) & 1u);   // RNE
    return (u16)(u >> 16);
}
__device__ __forceinline__ float sigm(float x) { return 1.0f / (1.0f + __expf(-x)); }
__device__ __forceinline__ float tanh_f(float x) { return 1.0f - 2.0f / (__expf(2.0f * x) + 1.0f); }
__device__ __forceinline__ void vmcnt0() { asm volatile("s_waitcnt vmcnt(0)" ::: "memory"); }

// ---------------------------------------------------------------------------
__global__ void zero_kernel(unsigned char* ws) {
    int i = blockIdx.x * blockDim.x + threadIdx.x;   // 16384 threads
    uint32_t* h0 = (uint32_t*)(ws + OFF_H);          // slot 0 = h(0): 131072 B
    for (int k = i; k < 32768; k += 16384) h0[k] = 0u;
    if (i < 256) ((uint32_t*)(ws + OFF_BAR))[i] = 0u;   // hbar + pcnt_z
}

// ---------------------------------------------------------------------------
__global__ void prep_kernel(const float* enc_W, const float* enc_U, const float* cell_W,
                            const float* cell_U, const float* conv_k, const float* back_W,
                            const float* fore_W, unsigned char* ws) {
    u16* encWt = (u16*)(ws + OFF_ENCWT);
    u16* encUt = (u16*)(ws + OFF_ENCUT);
    u16* cellT = (u16*)(ws + OFF_CELLT);
    u16* convKt = (u16*)(ws + OFF_CONVKT);
    u16* bwt = (u16*)(ws + OFF_BWT);
    u16* fwt = (u16*)(ws + OFF_FWT);
    int idx = blockIdx.x * blockDim.x + threadIdx.x;
    int stride = gridDim.x * blockDim.x;
    for (int i = idx; i < 262144; i += stride) {
        int n = i >> 8, k = i & 255;
        encWt[i] = f2bf(enc_W[k * 1024 + n]);
        encUt[i] = f2bf(enc_U[k * 1024 + n]);
        cellT[i] = f2bf(cell_W[k * 1024 + n] + cell_U[k * 1024 + n]);
    }
    for (int i = idx; i < 81920; i += stride) {
        int u = i / 320, rem = i - u * 320;
        convKt[i] = f2bf(conv_k[rem * 256 + u]);
    }
    for (int i = idx; i < 16384; i += stride) {
        int n = i >> 8, k = i & 255;
        bwt[i] = f2bf(back_W[k * 64 + n]);
    }
    for (int i = idx; i < 8192; i += stride) {
        int n = i >> 8, k = i & 255;
        fwt[i] = f2bf(fore_W[k * 32 + n]);
    }
}

// ---------------------------------------------------------------------------
// Conv1D(same,k=5)+bias+ReLU as MFMA GEMM (verbatim round-1 passing code)
__global__ __launch_bounds__(256) void conv_kernel(const float* __restrict__ in,
                                                   const float* __restrict__ conv_b,
                                                   unsigned char* ws) {
    const u16* kt = (const u16*)(ws + OFF_CONVKT);
    u16* xout = (u16*)(ws + OFF_X);
    int w = threadIdx.x >> 6, lane = threadIdx.x & 63;
    int m = lane & 15, q = lane >> 4;
    int mt = blockIdx.x * 4 + w;
    int r0 = mt * 16;
    int b = r0 >> 9;
    int l0 = r0 & 511;

    fx4 acc[16];
#pragma unroll
    for (int nt = 0; nt < 16; ++nt) acc[nt] = (fx4){0.f, 0.f, 0.f, 0.f};

#pragma unroll
    for (int s = 0; s < 10; ++s) {
        int k0 = s * 32 + q * 8;
        int kk = k0 >> 6, c = k0 & 63;
        int l2 = l0 + m + kk - 2;
        bf16x8 af = {0, 0, 0, 0, 0, 0, 0, 0};
        if (l2 >= 0 && l2 < 512) {
            const float* src = in + (((b << 9) + l2) << 6) + c;
            fx4 f0 = *(const fx4*)src;
            fx4 f1 = *(const fx4*)(src + 4);
            af[0] = (short)f2bf(f0[0]); af[1] = (short)f2bf(f0[1]);
            af[2] = (short)f2bf(f0[2]); af[3] = (short)f2bf(f0[3]);
            af[4] = (short)f2bf(f1[0]); af[5] = (short)f2bf(f1[1]);
            af[6] = (short)f2bf(f1[2]); af[7] = (short)f2bf(f1[3]);
        }
#pragma unroll
        for (int nt = 0; nt < 16; ++nt) {
            bf16x8 bf = *(const bf16x8*)(kt + (nt * 16 + m) * 320 + k0);
            acc[nt] = MFMA16(af, bf, acc[nt]);
        }
    }
#pragma unroll
    for (int nt = 0; nt < 16; ++nt) {
        int u = nt * 16 + m;
        float bias = conv_b[u];
#pragma unroll
        for (int r = 0; r < 4; ++r) {
            float v = acc[nt][r] + bias;
            v = v > 0.f ? v : 0.f;
            int row = r0 + q * 4 + r;
            xout[row * 256 + u] = f2bf(v);
        }
    }
}

// ---------------------------------------------------------------------------
// Encoder, producer/consumer split — all blocks are 256 threads (the ONLY
// launch shape proven to work on this harness; rounds 2-6 all failed to launch
// with 512/1024-thread or >64KB-LDS blocks).
// Blocks 0..63  : consumers (g=bid&15, p=bid>>4) — round-1 enc_kernel with the
//   x-part removed: only U-fragments in VGPRs (128), h-part MFMAs, gates, and
//   the PROVEN sc-store/vmcnt/atomic/poll h-exchange. z comes from the ring.
//   h-stores go through a 2KB LDS transpose -> 256 dwordx2 sc-stores.
// Blocks 64..127: producers (idx=bid-64) — z[t] = x_t@W_enc + enc_b for their
//   64 units x 4 gates, dwordx4 sc-stores into the 8-deep ring; signal pcnt_z
//   (+1/WG/step); backpressure = consumers' hbar (slot reuse needs hbar>=4(t-6)).
__global__ __launch_bounds__(256, 1) void enc_fused(const float* __restrict__ enc_b,
                                                    unsigned char* ws) {
    __shared__ u16 hbuf[1024];   // [16 rows][64 units] transpose buffer (2KB)
    int tid = threadIdx.x;
    int w = tid >> 6, lane = tid & 63, m = lane & 15, q = lane >> 4;
    int bid = blockIdx.x;
    u16* H = (u16*)(ws + OFF_H);
    int budget = POLL_BUDGET;

    if (bid >= 64) {
        // ================= producer =================
        int idx = bid - 64, g = idx & 15, p = idx >> 4;
        int b0 = g * 16;
        int un0 = p * 64 + w * 16;
        const u16* encWt = (const u16*)(ws + OFF_ENCWT);
        const u16* xbf = (const u16*)(ws + OFF_X);
        float* ringg = (float*)(ws + RING_OFF + (size_t)g * 524288u);
        int* hbar = (int*)(ws + OFF_BAR + g * 64);
        int* pz = (int*)(ws + OFF_BAR + g * 64 + 32);

        bf16x8 wfr[4][8];
        float bi[4];
#pragma unroll
        for (int j = 0; j < 4; ++j) {
            int row = j * 256 + un0 + m;
            bi[j] = enc_b[row];
#pragma unroll
            for (int ks = 0; ks < 8; ++ks)
                wfr[j][ks] = *(const bf16x8*)(encWt + row * 256 + ks * 32 + q * 8);
        }
        const u16* xrow = xbf + (size_t)(b0 + m) * (512 * 256) + q * 8;
        bf16x8 xa[8];
#pragma unroll
        for (int s = 0; s < 8; ++s) xa[s] = *(const bf16x8*)(xrow + s * 32);

        for (int t = 0; t < 512; ++t) {
            fx4 a0 = (fx4){bi[0], bi[0], bi[0], bi[0]};
            fx4 a1 = (fx4){bi[1], bi[1], bi[1], bi[1]};
            fx4 a2 = (fx4){bi[2], bi[2], bi[2], bi[2]};
            fx4 a3 = (fx4){bi[3], bi[3], bi[3], bi[3]};
#pragma unroll
            for (int ks = 0; ks < 8; ++ks) {
                a0 = MFMA16(xa[ks], wfr[0][ks], a0);
                a1 = MFMA16(xa[ks], wfr[1][ks], a1);
                a2 = MFMA16(xa[ks], wfr[2][ks], a2);
                a3 = MFMA16(xa[ks], wfr[3][ks], a3);
            }
            // slot layout: [j][u][16 r] fp32; lane (m,q) stores rows q*4..+3
            float* zs = ringg + (t & 7) * 16384 + (un0 + m) * 16 + q * 4;
            asm volatile("global_store_dwordx4 %0, %1, off sc0 sc1" :: "v"(zs), "v"(a0) : "memory");
            asm volatile("global_store_dwordx4 %0, %1, off sc0 sc1" :: "v"(zs + 4096), "v"(a1) : "memory");
            asm volatile("global_store_dwordx4 %0, %1, off sc0 sc1" :: "v"(zs + 8192), "v"(a2) : "memory");
            asm volatile("global_store_dwordx4 %0, %1, off sc0 sc1" :: "v"(zs + 12288), "v"(a3) : "memory");
            if (t < 511) {
                const u16* xA = xrow + (size_t)(t + 1) * 256;   // prefetch next x
#pragma unroll
                for (int s = 0; s < 8; ++s) xa[s] = *(const bf16x8*)(xA + s * 32);
                if (tid == 0 && t >= 7) {
                    // next step overwrites slot (t+1)&7 (holds z[t-7]); all 4
                    // consumer WGs must have finished reading step t-7:
                    int tgt = 4 * (t - 6);
                    while (__hip_atomic_load(hbar, __ATOMIC_RELAXED, __HIP_MEMORY_SCOPE_AGENT) < tgt
                           && --budget > 0) {}
                }
            }
            vmcnt0();                 // z stores (and prefetch) complete
            __syncthreads();
            if (tid == 0)
                __hip_atomic_fetch_add(pz, 1, __ATOMIC_RELAXED, __HIP_MEMORY_SCOPE_AGENT);
        }
        return;
    }

    // ================= consumer =================
    int g = bid & 15, p = bid >> 4;
    int b0 = g * 16;
    int un0 = p * 64 + w * 16;
    const u16* encUt = (const u16*)(ws + OFF_ENCUT);
    const float* ringg = (const float*)(ws + RING_OFF + (size_t)g * 524288u);
    float* csaveg = (float*)(ws + OFF_X + (size_t)g * 4194304u);
    int* hbar = (int*)(ws + OFF_BAR + g * 64);
    int* pz = (int*)(ws + OFF_BAR + g * 64 + 32);

    bf16x8 ufrag[4][8];
#pragma unroll
    for (int gi = 0; gi < 4; ++gi) {
#pragma unroll
        for (int s = 0; s < 8; ++s)
            ufrag[gi][s] = *(const bf16x8*)(encUt + (gi * 256 + un0 + m) * 256 + s * 32 + q * 8);
    }
    float creg[4] = {0.f, 0.f, 0.f, 0.f};

    for (int t = 0; t < 512; ++t) {
        // ---- wait: z[t] fully stored (pz>=4(t+1)) AND peers' h(t) done ----
        if (lane == 0) {
            int tgtz = 4 * (t + 1), tgth = 4 * t;
            while (--budget > 0) {
                int vz = __hip_atomic_load(pz, __ATOMIC_RELAXED, __HIP_MEMORY_SCOPE_AGENT);
                int vh = __hip_atomic_load(hbar, __ATOMIC_RELAXED, __HIP_MEMORY_SCOPE_AGENT);
                if (vz >= tgtz && vh >= tgth) break;
            }
        }
        asm volatile("" ::: "memory");   // don't hoist loads above the poll

        // ---- h(t) fragments (plain loads: rotating, never-cached lines) ----
        const u16* hA = H + (size_t)t * 65536 + (b0 + m) * 256 + q * 8;
        bf16x8 ha[8];
#pragma unroll
        for (int s = 0; s < 8; ++s) ha[s] = *(const bf16x8*)(hA + s * 32);
        // ---- z[t] (sc loads: ring slots are recycled every 8 steps) ----
        const float* zb = ringg + (t & 7) * 16384 + (un0 + m) * 16 + q * 4;
        fx4 z0, z1, z2, z3;
        asm volatile("global_load_dwordx4 %0, %1, off sc0 sc1" : "=v"(z0) : "v"(zb));
        asm volatile("global_load_dwordx4 %0, %1, off sc0 sc1" : "=v"(z1) : "v"(zb + 4096));
        asm volatile("global_load_dwordx4 %0, %1, off sc0 sc1" : "=v"(z2) : "v"(zb + 8192));
        asm volatile("global_load_dwordx4 %0, %1, off sc0 sc1" : "=v"(z3) : "v"(zb + 12288));

        fx4 acc[4];
#pragma unroll
        for (int gi = 0; gi < 4; ++gi) acc[gi] = (fx4){0.f, 0.f, 0.f, 0.f};
#pragma unroll
        for (int s = 0; s < 8; ++s) {
#pragma unroll
            for (int gi = 0; gi < 4; ++gi)
                acc[gi] = MFMA16(ha[s], ufrag[gi][s], acc[gi]);
        }
        vmcnt0();                                  // z arrived
        __builtin_amdgcn_sched_barrier(0);

        float hreg[4];
#pragma unroll
        for (int r = 0; r < 4; ++r) {
            float pi = acc[0][r] + z0[r];
            float pf = acc[1][r] + z1[r];
            float pg = acc[2][r] + z2[r];
            float po = acc[3][r] + z3[r];
            float cv = sigm(pf) * creg[r] + sigm(pi) * tanh_f(pg);
            creg[r] = cv;
            hreg[r] = sigm(po) * tanh_f(cv);
        }
        // ---- LDS transpose, then coalesced sc-stores of h(t+1) ----
#pragma unroll
        for (int r = 0; r < 4; ++r)
            hbuf[(q * 4 + r) * 64 + w * 16 + m] = f2bf(hreg[r]);
        __syncthreads();
        {
            int row = tid >> 4, c4 = (tid & 15) * 4;
            u32x2 hv = *(const u32x2*)&hbuf[row * 64 + c4];
            const u16* hw = H + (size_t)(t + 1) * 65536 + (b0 + row) * 256 + p * 64 + c4;
            asm volatile("global_store_dwordx2 %0, %1, off sc0 sc1" :: "v"(hw), "v"(hv) : "memory");
        }
        vmcnt0();          // h(t+1) device-visible before the signal
        __syncthreads();   // also guards hbuf reuse next iteration
        if (tid == 0)
            __hip_atomic_fetch_add(hbar, 1, __ATOMIC_RELAXED, __HIP_MEMORY_SCOPE_AGENT);
    }

    // hand off c to the decoder (normal stores; kernel-end flush makes visible)
#pragma unroll
    for (int r = 0; r < 4; ++r)
        csaveg[(q * 4 + r) * 256 + un0 + m] = creg[r];
}

// ---------------------------------------------------------------------------
// Decoder: verbatim round-1 passing code (runs after enc_fused; overwrites the
// then-dead ring region at H[513..576]).
__global__ __launch_bounds__(256, 1) void dec_kernel(const float* __restrict__ cell_b,
                                                     unsigned char* ws) {
    int tid = threadIdx.x;
    int w = tid >> 6, lane = tid & 63, m = lane & 15, q = lane >> 4;
    int bid = blockIdx.x;
    int g = bid & 15, p = bid >> 4;
    int b0 = g * 16;
    int un0 = p * 64 + w * 16;
    int budget = POLL_BUDGET;

    const u16* cellT = (const u16*)(ws + OFF_CELLT);
    u16* H = (u16*)(ws + OFF_H);
    const float* csaveg = (const float*)(ws + OFF_X + (size_t)g * 4194304u);
    int* bar = (int*)(ws + OFF_BAR + g * 64);

    bf16x8 wfrag[4][8];
#pragma unroll
    for (int gi = 0; gi < 4; ++gi) {
#pragma unroll
        for (int s = 0; s < 8; ++s)
            wfrag[gi][s] = *(const bf16x8*)(cellT + (gi * 256 + un0 + m) * 256 + s * 32 + q * 8);
    }
    float bi[4], creg[4];
#pragma unroll
    for (int gi = 0; gi < 4; ++gi) bi[gi] = cell_b[gi * 256 + un0 + m];
#pragma unroll
    for (int r = 0; r < 4; ++r) creg[r] = csaveg[(q * 4 + r) * 256 + un0 + m];

    for (int t = 0; t < 64; ++t) {
        if (lane == 0) {
            int tgt = 2048 + 4 * t;   // encoder left hbar at 4*512 = 2048
            while (__hip_atomic_load(bar, __ATOMIC_RELAXED, __HIP_MEMORY_SCOPE_AGENT) < tgt
                   && --budget > 0) {}
        }
        asm volatile("" ::: "memory");

        const u16* hA = H + (size_t)(512 + t) * 65536 + (b0 + m) * 256 + q * 8;
        bf16x8 ha[8];
#pragma unroll
        for (int s = 0; s < 8; ++s) ha[s] = *(const bf16x8*)(hA + s * 32);
        fx4 acc[4];
#pragma unroll
        for (int gi = 0; gi < 4; ++gi) acc[gi] = (fx4){bi[gi], bi[gi], bi[gi], bi[gi]};
#pragma unroll
        for (int s = 0; s < 8; ++s) {
#pragma unroll
            for (int gi = 0; gi < 4; ++gi)
                acc[gi] = MFMA16(ha[s], wfrag[gi][s], acc[gi]);
        }

        const u16* hw = H + (size_t)(513 + t) * 65536 + un0 + m;
#pragma unroll
        for (int r = 0; r < 4; ++r) {
            float cv = sigm(acc[1][r]) * creg[r] + sigm(acc[0][r]) * tanh_f(acc[2][r]);
            creg[r] = cv;
            float hv = sigm(acc[3][r]) * tanh_f(cv);
            uint32_t hb = (uint32_t)f2bf(hv);
            const u16* hp = hw + (b0 + q * 4 + r) * 256;
            asm volatile("global_store_short %0, %1, off sc0 sc1" :: "v"(hp), "v"(hb) : "memory");
        }
        vmcnt0();
        __syncthreads();
        if (tid == 0)
            __hip_atomic_fetch_add(bar, 1, __ATOMIC_RELAXED, __HIP_MEMORY_SCOPE_AGENT);
    }
}

// ---------------------------------------------------------------------------
// out[(b*seqlen+s)*ncols+col] = H-slot A[s][b][:] @ Bt[col][:] + bias[col]
__global__ __launch_bounds__(256) void out_gemm(const u16* __restrict__ A,
                                                const u16* __restrict__ Bt,
                                                const float* __restrict__ bias,
                                                float* __restrict__ out,
                                                int ncols, int seqlen) {
    int w = threadIdx.x >> 6, lane = threadIdx.x & 63, m = lane & 15, q = lane >> 4;
    int mt = blockIdx.x * 4 + w;
    int s = mt >> 4;
    int b0 = (mt & 15) * 16;
    bf16x8 af[8];
    const u16* Arow = A + ((size_t)s * 256 + b0 + m) * 256 + q * 8;
#pragma unroll
    for (int ss = 0; ss < 8; ++ss) af[ss] = *(const bf16x8*)(Arow + ss * 32);
    int ntiles = ncols >> 4;
    for (int nt = 0; nt < ntiles; ++nt) {
        fx4 acc = (fx4){0.f, 0.f, 0.f, 0.f};
#pragma unroll
        for (int ss = 0; ss < 8; ++ss) {
            bf16x8 bf = *(const bf16x8*)(Bt + (nt * 16 + m) * 256 + ss * 32 + q * 8);
            acc = MFMA16(af[ss], bf, acc);
        }
        int col = nt * 16 + m;
        float bv = bias[col];
#pragma unroll
        for (int r = 0; r < 4; ++r) {
            int b = b0 + q * 4 + r;
            out[((size_t)b * seqlen + s) * ncols + col] = acc[r] + bv;
        }
    }
}

// ---------------------------------------------------------------------------
extern "C" void kernel_launch(void* const* d_in, const int* in_sizes, int n_in,
                              void* d_out, int out_size, void* d_ws, size_t ws_size,
                              hipStream_t stream) {
    const float* inputs = (const float*)d_in[0];
    const float* conv_k = (const float*)d_in[1];
    const float* conv_b = (const float*)d_in[2];
    const float* enc_W  = (const float*)d_in[3];
    const float* enc_U  = (const float*)d_in[4];
    const float* enc_b  = (const float*)d_in[5];
    const float* cell_W = (const float*)d_in[6];
    const float* cell_U = (const float*)d_in[7];
    const float* cell_b = (const float*)d_in[8];
    const float* fore_W = (const float*)d_in[9];
    const float* fore_b = (const float*)d_in[10];
    const float* back_W = (const float*)d_in[11];
    const float* back_b = (const float*)d_in[12];
    unsigned char* ws = (unsigned char*)d_ws;
    float* out = (float*)d_out;

    zero_kernel<<<64, 256, 0, stream>>>(ws);
    prep_kernel<<<1024, 256, 0, stream>>>(enc_W, enc_U, cell_W, cell_U, conv_k, back_W, fore_W, ws);
    conv_kernel<<<2048, 256, 0, stream>>>(inputs, conv_b, ws);
    enc_fused<<<128, 256, 0, stream>>>(enc_b, ws);
    dec_kernel<<<64, 256, 0, stream>>>(cell_b, ws);

    const u16* H = (const u16*)(ws + OFF_H);
    // backcast: slots 1..512 -> out[b][l][64] at float offset 524288
    out_gemm<<<2048, 256, 0, stream>>>(H + (size_t)1 * 65536, (const u16*)(ws + OFF_BWT),
                                       back_b, out + 524288, 64, 512);
    // forecast: slots 513..576 -> out[b][j][32]
    out_gemm<<<256, 256, 0, stream>>>(H + (size_t)513 * 65536, (const u16*)(ws + OFF_FWT),
                                      fore_b, out, 32, 64);
}